// Round 5
// baseline (3544.154 us; speedup 1.0000x reference)
//
#include <hip/hip_runtime.h>

#define HH 128
#define WW 128

typedef __bf16 bf16;
typedef bf16 bf16x8 __attribute__((ext_vector_type(8)));
typedef float f32x4 __attribute__((ext_vector_type(4)));

__device__ __forceinline__ float hsig(float x) {
    return fminf(fmaxf(fmaf(0.2f, x, 0.5f), 0.f), 1.f);
}
__device__ __forceinline__ float ftanh(float x) {
    // (e^2x - 1) / (e^2x + 1); |x| here is bounded (~<=16) so no overflow
    const float u = __expf(2.f * fminf(x, 40.f));
    return (u - 1.f) * __builtin_amdgcn_rcpf(u + 1.f);
}

// ---- one-time weight prep: fp32 [tap][ci][cout] -> bf16 Wt[l][tap][cout][ci64]
// ci64: x cins at [0,CX), h cins at [CX,CX+32), zero pad to 64. (CX=16 for l=0)
__global__ void prep_weights(const float* __restrict__ Wx0, const float* __restrict__ Wh0,
                             const float* __restrict__ Wx1, const float* __restrict__ Wh1,
                             const float* __restrict__ Wx2, const float* __restrict__ Wh2,
                             const float* __restrict__ Wx3, const float* __restrict__ Wh3,
                             bf16* __restrict__ Wt)
{
    int idx = blockIdx.x * 256 + threadIdx.x;      // 4*9*128*64 = 294912
    if (idx >= 4 * 9 * 128 * 64) return;
    const int l = idx / 73728;
    int r = idx - l * 73728;
    const int tap = r / (128 * 64);
    r -= tap * 128 * 64;
    const int co = r >> 6;
    const int ci = r & 63;
    const int CX = (l == 0) ? 16 : 32;
    const float* Wx = (l == 0) ? Wx0 : (l == 1) ? Wx1 : (l == 2) ? Wx2 : Wx3;
    const float* Wh = (l == 0) ? Wh0 : (l == 1) ? Wh1 : (l == 2) ? Wh2 : Wh3;
    float v = 0.f;
    if (ci < CX)           v = Wx[((size_t)tap * CX + ci) * 128 + co];
    else if (ci < CX + 32) v = Wh[((size_t)tap * 32 + (ci - CX)) * 128 + co];
    Wt[(size_t)l * 73728 + ((size_t)tap * 128 + co) * 64 + ci] = (bf16)v;
}

constexpr int ST = 72;   // ci stride (elems) in LDS halo

__device__ __forceinline__ void loadB(bf16x8 B[2][8], const bf16* __restrict__ wb0, int tap) {
    const bf16* wt = wb0 + (size_t)tap * 8192;     // 128*64
    #pragma unroll
    for (int nb = 0; nb < 8; ++nb) {
        B[0][nb] = *(const bf16x8*)(wt + nb * 1024);
        B[1][nb] = *(const bf16x8*)(wt + nb * 1024 + 32);
    }
}

__device__ __forceinline__ void mfma_tap(f32x4 acc[8], const bf16* sact,
                                         bf16x8 B[2][8],
                                         int wv, int col, int krow, int tap) {
    const int dy = tap / 3, dx = tap - dy * 3;
    const int r0 = (wv + dy) * 18 + col + dx;
    bf16x8 A[2];
    A[0] = *(const bf16x8*)(&sact[r0 * ST + krow * 8]);
    A[1] = *(const bf16x8*)(&sact[r0 * ST + 32 + krow * 8]);
    #pragma unroll
    for (int kb = 0; kb < 2; ++kb)
        #pragma unroll
        for (int nb = 0; nb < 8; ++nb)
            acc[nb] = __builtin_amdgcn_mfma_f32_16x16x32_bf16(A[kb], B[kb][nb], acc[nb], 0, 0, 0);
}

// One ConvLSTM step via implicit-GEMM MFMA.
// Block: 16(w) x 4(h) pixel tile x batch; wave wv owns pixel row wv (M=16 x's).
// c state is PLANAR [b][y][f][x] (float4 per lane); h stays [b][y][x][32] bf16.
template<int CINX, bool XF32>
__global__ __launch_bounds__(256, 4)
void lstm_step(const void* __restrict__ xin_, size_t xbs,
               const bf16* __restrict__ res,
               const bf16* __restrict__ Wt,
               const float* __restrict__ bias,
               const bf16* __restrict__ hprev,
               float* __restrict__ cst,
               bf16* __restrict__ hout,
               float* __restrict__ outf,
               const int mode)   // 0 raw, 1 relu(x), 2 relu(x+res)
{
    __shared__ bf16 sact[108 * ST];        // halo 6y x 18x pixels, 64 ci each

    const int tid = threadIdx.x;
    const int bx = blockIdx.x, by = blockIdx.y, bb = blockIdx.z;

    const int lane = tid & 63;
    const int wv   = tid >> 6;        // wave id = output row within tile
    const int col  = lane & 15;       // A row (x) / C col (cout%16) / B col
    const int krow = lane >> 4;       // k-slice / C row block

    // ---- prefetch c state (independent of staging) ----
    const int gy = by * 4 + wv;
    const int x0 = bx * 16 + krow * 4;
    f32x4 cpre[2];
    size_t cidx[2];
    #pragma unroll
    for (int h2 = 0; h2 < 2; ++h2) {
        const int f = h2 * 16 + col;
        cidx[h2] = (((size_t)bb * HH + gy) * 32 + f) * WW + x0;
        cpre[h2] = *(const f32x4*)(cst + cidx[h2]);
    }

    // ---- stage halo (zeros OOB / pad), bf16, [pix][ci] ----
    for (int i = tid; i < 108 * 8; i += 256) {
        const int pix = i >> 3, g = i & 7;           // g: 8-ci chunk
        const int hy = pix / 18, hx = pix - hy * 18;
        const int sy = by * 4 - 1 + hy, sx = bx * 16 - 1 + hx;
        const bool inb = ((unsigned)sy < HH) && ((unsigned)sx < WW);
        float v[8];
        #pragma unroll
        for (int j = 0; j < 8; ++j) v[j] = 0.f;
        if (inb) {
            const size_t poff = (size_t)sy * WW + sx;
            if (g * 8 < CINX) {                       // x part
                if constexpr (XF32) {
                    const float* xp = (const float*)xin_ + (size_t)bb * xbs + poff * CINX + g * 8;
                    const f32x4 a = *(const f32x4*)xp;
                    const f32x4 b = *(const f32x4*)(xp + 4);
                    v[0] = a.x; v[1] = a.y; v[2] = a.z; v[3] = a.w;
                    v[4] = b.x; v[5] = b.y; v[6] = b.z; v[7] = b.w;
                } else {
                    const bf16* xp = (const bf16*)xin_ + (size_t)bb * xbs + poff * CINX + g * 8;
                    const bf16x8 a = *(const bf16x8*)xp;
                    #pragma unroll
                    for (int j = 0; j < 8; ++j) v[j] = (float)a[j];
                    if (mode == 2) {
                        const bf16x8 rr = *(const bf16x8*)(res + ((size_t)bb * HH * WW + poff) * 32 + g * 8);
                        #pragma unroll
                        for (int j = 0; j < 8; ++j) v[j] += (float)rr[j];
                    }
                    if (mode != 0) {
                        #pragma unroll
                        for (int j = 0; j < 8; ++j) v[j] = fmaxf(v[j], 0.f);
                    }
                }
            } else if (g * 8 < CINX + 32) {           // h part
                const bf16* hp = hprev + ((size_t)bb * HH * WW + poff) * 32 + (g * 8 - CINX);
                const bf16x8 a = *(const bf16x8*)hp;
                #pragma unroll
                for (int j = 0; j < 8; ++j) v[j] = (float)a[j];
            }
        }
        bf16x8 w;
        #pragma unroll
        for (int j = 0; j < 8; ++j) w[j] = (bf16)v[j];
        *(bf16x8*)(&sact[pix * ST + g * 8]) = w;
    }
    __syncthreads();

    f32x4 acc[8];
    #pragma unroll
    for (int nb = 0; nb < 8; ++nb) {
        const float bv = bias[nb * 16 + col];
        acc[nb] = (f32x4){bv, bv, bv, bv};
    }

    const bf16* __restrict__ wb0 = Wt + (size_t)col * 64 + krow * 8;

    // ---- 9-tap loop, B fragments software-pipelined one tap ahead ----
    bf16x8 BA[2][8], BB[2][8];
    loadB(BA, wb0, 0);
    #pragma unroll 1
    for (int k = 0; k < 4; ++k) {
        loadB(BB, wb0, 2 * k + 1);
        mfma_tap(acc, sact, BA, wv, col, krow, 2 * k);
        loadB(BA, wb0, 2 * k + 2);
        mfma_tap(acc, sact, BB, wv, col, krow, 2 * k + 1);
    }
    mfma_tap(acc, sact, BA, wv, col, krow, 8);

    // ---- lane-local LSTM pointwise ----
    // z(y=gy, x=x0+j, cout=nb*16+col); gate = nb>>1, filter f = (nb&1)*16+col
    #pragma unroll
    for (int h2 = 0; h2 < 2; ++h2) {
        const int f = h2 * 16 + col;
        f32x4 cn4, hn4;
        #pragma unroll
        for (int j = 0; j < 4; ++j) {
            const float zi = acc[0 + h2][j];
            const float zf = acc[2 + h2][j];
            const float zg = acc[4 + h2][j];
            const float zo = acc[6 + h2][j];
            const float ig = hsig(zi), fg = hsig(zf);
            const float gg = ftanh(zg), og = hsig(zo);
            const float cn = fmaf(fg, cpre[h2][j], ig * gg);
            cn4[j] = cn;
            hn4[j] = og * ftanh(cn);
        }
        *(f32x4*)(cst + cidx[h2]) = cn4;
        const size_t hb = (((size_t)bb * HH + gy) * WW + x0) * 32 + f;
        if (outf) {
            #pragma unroll
            for (int j = 0; j < 4; ++j) outf[hb + (size_t)j * 32] = hn4[j];
        } else {
            #pragma unroll
            for (int j = 0; j < 4; ++j) hout[hb + (size_t)j * 32] = (bf16)hn4[j];
        }
    }
}

extern "C" void kernel_launch(void* const* d_in, const int* in_sizes, int n_in,
                              void* d_out, int out_size, void* d_ws, size_t ws_size,
                              hipStream_t stream) {
    const float* x = (const float*)d_in[0];
    const float* Wx[4] = {(const float*)d_in[1], (const float*)d_in[4],
                          (const float*)d_in[7], (const float*)d_in[10]};
    const float* Wh[4] = {(const float*)d_in[2], (const float*)d_in[5],
                          (const float*)d_in[8], (const float*)d_in[11]};
    const float* bs[4] = {(const float*)d_in[3], (const float*)d_in[6],
                          (const float*)d_in[9], (const float*)d_in[12]};
    float* out = (float*)d_out;

    const size_t S  = (size_t)4 * HH * WW * 32;   // one [B,H,W,32] buffer (elements)
    const size_t HB = (size_t)HH * WW * 32;       // per-batch stride (elements)
    const size_t WT = (size_t)4 * 73728;          // transposed weights (bf16 elems)

    bf16* wt  = (bf16*)d_ws;
    bf16* hb  = wt + WT;
    float* cb = (float*)(hb + 8 * S);
    bf16 *hA[4], *hB[4]; float* cs[4];
    for (int l = 0; l < 4; ++l) {
        hA[l] = hb + (size_t)(2 * l + 0) * S;
        hB[l] = hb + (size_t)(2 * l + 1) * S;
        cs[l] = cb + (size_t)l * S;
    }
    for (int l = 0; l < 4; ++l) {
        hipMemsetAsync(hA[l], 0, S * sizeof(bf16), stream);
        hipMemsetAsync(cs[l], 0, S * sizeof(float), stream);
    }

    prep_weights<<<1152, 256, 0, stream>>>(Wx[0], Wh[0], Wx[1], Wh[1],
                                           Wx[2], Wh[2], Wx[3], Wh[3], wt);

    dim3 grid(WW / 16, HH / 4, 4);
    dim3 blk(256);

    bf16* hp[4] = {hA[0], hA[1], hA[2], hA[3]};
    bf16* hc[4] = {hB[0], hB[1], hB[2], hB[3]};

    for (int t = 0; t < 8; ++t) {
        lstm_step<16, true><<<grid, blk, 0, stream>>>(
            x + (size_t)t * HH * WW * 16, (size_t)8 * HH * WW * 16, nullptr,
            wt + 0 * 73728, bs[0], hp[0], cs[0], hc[0], nullptr, 0);
        lstm_step<32, false><<<grid, blk, 0, stream>>>(
            hc[0], HB, nullptr,
            wt + 1 * 73728, bs[1], hp[1], cs[1], hc[1], nullptr, 0);
        lstm_step<32, false><<<grid, blk, 0, stream>>>(
            hc[1], HB, nullptr,
            wt + 2 * 73728, bs[2], hp[2], cs[2], hc[2], nullptr, 1);
        lstm_step<32, false><<<grid, blk, 0, stream>>>(
            hc[2], HB, hc[0],
            wt + 3 * 73728, bs[3], hp[3], cs[3], hc[3], (t == 7) ? out : nullptr, 2);

        for (int l = 0; l < 4; ++l) { bf16* tmp = hp[l]; hp[l] = hc[l]; hc[l] = tmp; }
    }
}

// Round 6
// 2308.502 us; speedup vs baseline: 1.5353x; 1.5353x over previous
//
#include <hip/hip_runtime.h>

#define HH 128
#define WW 128

typedef __bf16 bf16;
typedef bf16 bf16x8 __attribute__((ext_vector_type(8)));
typedef float f32x4 __attribute__((ext_vector_type(4)));

__device__ __forceinline__ float hsig(float x) {
    return fminf(fmaxf(fmaf(0.2f, x, 0.5f), 0.f), 1.f);
}
__device__ __forceinline__ float ftanh(float x) {
    // (e^2x - 1) / (e^2x + 1); z is bounded (|z| small) so no overflow
    const float u = __expf(2.f * fminf(x, 40.f));
    return (u - 1.f) * __builtin_amdgcn_rcpf(u + 1.f);
}

// ---- one-time weight prep: fp32 [tap][ci][cout] -> bf16 Wt[l][tap][cout][ci64]
// ci64: x cins at [0,CX), h cins at [CX,CX+32), zero pad to 64. (CX=16 for l=0)
__global__ void prep_weights(const float* __restrict__ Wx0, const float* __restrict__ Wh0,
                             const float* __restrict__ Wx1, const float* __restrict__ Wh1,
                             const float* __restrict__ Wx2, const float* __restrict__ Wh2,
                             const float* __restrict__ Wx3, const float* __restrict__ Wh3,
                             bf16* __restrict__ Wt)
{
    int idx = blockIdx.x * 256 + threadIdx.x;      // 4*9*128*64 = 294912
    if (idx >= 4 * 9 * 128 * 64) return;
    const int l = idx / 73728;
    int r = idx - l * 73728;
    const int tap = r / (128 * 64);
    r -= tap * 128 * 64;
    const int co = r >> 6;
    const int ci = r & 63;
    const int CX = (l == 0) ? 16 : 32;
    const float* Wx = (l == 0) ? Wx0 : (l == 1) ? Wx1 : (l == 2) ? Wx2 : Wx3;
    const float* Wh = (l == 0) ? Wh0 : (l == 1) ? Wh1 : (l == 2) ? Wh2 : Wh3;
    float v = 0.f;
    if (ci < CX)           v = Wx[((size_t)tap * CX + ci) * 128 + co];
    else if (ci < CX + 32) v = Wh[((size_t)tap * 32 + (ci - CX)) * 128 + co];
    Wt[(size_t)l * 73728 + ((size_t)tap * 128 + co) * 64 + ci] = (bf16)v;
}

constexpr int ST = 72;   // ci stride (elems) in LDS halo

// One ConvLSTM step via implicit-GEMM MFMA.
// Block: 16(w) x 8(h) pixel tile x batch; 8 waves, wave wv = pixel row wv.
// Memory layouts identical to the proven R4 kernel: h [B,H,W,32] bf16,
// c [B,H,W,32] fp32, scalar epilogue loads/stores (L2/L3-friendly).
template<int CINX, bool XF32>
__global__ __launch_bounds__(512, 4)
void lstm_step(const void* __restrict__ xin_, size_t xbs,
               const bf16* __restrict__ res,
               const bf16* __restrict__ Wt,
               const float* __restrict__ bias,
               const bf16* __restrict__ hprev,
               float* __restrict__ cst,
               bf16* __restrict__ hout,
               float* __restrict__ outf,
               const int mode)   // 0 raw, 1 relu(x), 2 relu(x+res)
{
    __shared__ bf16 sact[180 * ST];        // halo 10y x 18x pixels, 64 ci each

    const int tid = threadIdx.x;
    const int bx = blockIdx.x, by = blockIdx.y, bb = blockIdx.z;

    // ---- stage halo (zeros OOB / pad), bf16, [pix][ci] ----
    for (int i = tid; i < 180 * 8; i += 512) {
        const int pix = i >> 3, g = i & 7;           // g: 8-ci chunk
        const int hy = pix / 18, hx = pix - hy * 18;
        const int sy = by * 8 - 1 + hy, sx = bx * 16 - 1 + hx;
        const bool inb = ((unsigned)sy < HH) && ((unsigned)sx < WW);
        float v[8];
        #pragma unroll
        for (int j = 0; j < 8; ++j) v[j] = 0.f;
        if (inb) {
            const size_t poff = (size_t)sy * WW + sx;
            if (g * 8 < CINX) {                       // x part
                if constexpr (XF32) {
                    const float* xp = (const float*)xin_ + (size_t)bb * xbs + poff * CINX + g * 8;
                    const f32x4 a = *(const f32x4*)xp;
                    const f32x4 b = *(const f32x4*)(xp + 4);
                    v[0] = a.x; v[1] = a.y; v[2] = a.z; v[3] = a.w;
                    v[4] = b.x; v[5] = b.y; v[6] = b.z; v[7] = b.w;
                } else {
                    const bf16* xp = (const bf16*)xin_ + (size_t)bb * xbs + poff * CINX + g * 8;
                    const bf16x8 a = *(const bf16x8*)xp;
                    #pragma unroll
                    for (int j = 0; j < 8; ++j) v[j] = (float)a[j];
                    if (mode == 2) {
                        const bf16x8 rr = *(const bf16x8*)(res + ((size_t)bb * HH * WW + poff) * 32 + g * 8);
                        #pragma unroll
                        for (int j = 0; j < 8; ++j) v[j] += (float)rr[j];
                    }
                    if (mode != 0) {
                        #pragma unroll
                        for (int j = 0; j < 8; ++j) v[j] = fmaxf(v[j], 0.f);
                    }
                }
            } else if (g * 8 < CINX + 32) {           // h part
                const bf16* hp = hprev + ((size_t)bb * HH * WW + poff) * 32 + (g * 8 - CINX);
                const bf16x8 a = *(const bf16x8*)hp;
                #pragma unroll
                for (int j = 0; j < 8; ++j) v[j] = (float)a[j];
            }
        }
        bf16x8 w;
        #pragma unroll
        for (int j = 0; j < 8; ++j) w[j] = (bf16)v[j];
        *(bf16x8*)(&sact[pix * ST + g * 8]) = w;
    }
    __syncthreads();

    const int lane = tid & 63;
    const int wv   = tid >> 6;        // wave id = output row within tile (0..7)
    const int col  = lane & 15;       // A row (x) / C col (cout%16) / B col
    const int krow = lane >> 4;       // k-slice / C row block

    f32x4 acc[8];
    #pragma unroll
    for (int nb = 0; nb < 8; ++nb) {
        const float bv = bias[nb * 16 + col];
        acc[nb] = (f32x4){bv, bv, bv, bv};
    }

    const bf16* __restrict__ wb0 = Wt + (size_t)col * 64 + krow * 8;

    // ---- 9-tap loop: single B buffer (register budget), TLP hides latency ----
    #pragma unroll 1
    for (int tap = 0; tap < 9; ++tap) {
        const bf16* wt = wb0 + (size_t)tap * 8192;     // 128*64
        bf16x8 B[2][8];
        #pragma unroll
        for (int nb = 0; nb < 8; ++nb) {
            B[0][nb] = *(const bf16x8*)(wt + nb * 1024);
            B[1][nb] = *(const bf16x8*)(wt + nb * 1024 + 32);
        }
        const int dy = tap / 3, dx = tap - dy * 3;
        const int r0 = (wv + dy) * 18 + col + dx;
        bf16x8 A[2];
        A[0] = *(const bf16x8*)(&sact[r0 * ST + krow * 8]);
        A[1] = *(const bf16x8*)(&sact[r0 * ST + 32 + krow * 8]);
        #pragma unroll
        for (int kb = 0; kb < 2; ++kb)
            #pragma unroll
            for (int nb = 0; nb < 8; ++nb)
                acc[nb] = __builtin_amdgcn_mfma_f32_16x16x32_bf16(A[kb], B[kb][nb], acc[nb], 0, 0, 0);
    }

    // ---- lane-local LSTM pointwise (R4 layout: [B,H,W,32], scalar ld/st) ----
    // z(y=gy, x=x0+j, cout=nb*16+col); gate = nb>>1, filter f = (nb&1)*16+col
    const int gy = by * 8 + wv;
    const int x0 = bx * 16 + krow * 4;
    #pragma unroll
    for (int j = 0; j < 4; ++j) {
        const int gx = x0 + j;
        const size_t pb = (((size_t)bb * HH + gy) * WW + gx) * 32;
        #pragma unroll
        for (int h2 = 0; h2 < 2; ++h2) {
            const int f = h2 * 16 + col;
            const float zi = acc[0 + h2][j];
            const float zf = acc[2 + h2][j];
            const float zg = acc[4 + h2][j];
            const float zo = acc[6 + h2][j];
            const float cold = cst[pb + f];
            const float ig = hsig(zi), fg = hsig(zf);
            const float gg = ftanh(zg), og = hsig(zo);
            const float cn = fmaf(fg, cold, ig * gg);
            cst[pb + f] = cn;
            const float hn = og * ftanh(cn);
            if (outf) outf[pb + f] = hn;
            else      hout[pb + f] = (bf16)hn;
        }
    }
}

extern "C" void kernel_launch(void* const* d_in, const int* in_sizes, int n_in,
                              void* d_out, int out_size, void* d_ws, size_t ws_size,
                              hipStream_t stream) {
    const float* x = (const float*)d_in[0];
    const float* Wx[4] = {(const float*)d_in[1], (const float*)d_in[4],
                          (const float*)d_in[7], (const float*)d_in[10]};
    const float* Wh[4] = {(const float*)d_in[2], (const float*)d_in[5],
                          (const float*)d_in[8], (const float*)d_in[11]};
    const float* bs[4] = {(const float*)d_in[3], (const float*)d_in[6],
                          (const float*)d_in[9], (const float*)d_in[12]};
    float* out = (float*)d_out;

    const size_t S  = (size_t)4 * HH * WW * 32;   // one [B,H,W,32] buffer (elements)
    const size_t HB = (size_t)HH * WW * 32;       // per-batch stride (elements)
    const size_t WT = (size_t)4 * 73728;          // transposed weights (bf16 elems)

    bf16* wt  = (bf16*)d_ws;
    bf16* hb  = wt + WT;
    float* cb = (float*)(hb + 8 * S);
    bf16 *hA[4], *hB[4]; float* cs[4];
    for (int l = 0; l < 4; ++l) {
        hA[l] = hb + (size_t)(2 * l + 0) * S;
        hB[l] = hb + (size_t)(2 * l + 1) * S;
        cs[l] = cb + (size_t)l * S;
    }
    for (int l = 0; l < 4; ++l) {
        hipMemsetAsync(hA[l], 0, S * sizeof(bf16), stream);
        hipMemsetAsync(cs[l], 0, S * sizeof(float), stream);
    }

    prep_weights<<<1152, 256, 0, stream>>>(Wx[0], Wh[0], Wx[1], Wh[1],
                                           Wx[2], Wh[2], Wx[3], Wh[3], wt);

    dim3 grid(WW / 16, HH / 8, 4);
    dim3 blk(512);

    bf16* hp[4] = {hA[0], hA[1], hA[2], hA[3]};
    bf16* hc[4] = {hB[0], hB[1], hB[2], hB[3]};

    for (int t = 0; t < 8; ++t) {
        lstm_step<16, true><<<grid, blk, 0, stream>>>(
            x + (size_t)t * HH * WW * 16, (size_t)8 * HH * WW * 16, nullptr,
            wt + 0 * 73728, bs[0], hp[0], cs[0], hc[0], nullptr, 0);
        lstm_step<32, false><<<grid, blk, 0, stream>>>(
            hc[0], HB, nullptr,
            wt + 1 * 73728, bs[1], hp[1], cs[1], hc[1], nullptr, 0);
        lstm_step<32, false><<<grid, blk, 0, stream>>>(
            hc[1], HB, nullptr,
            wt + 2 * 73728, bs[2], hp[2], cs[2], hc[2], nullptr, 1);
        lstm_step<32, false><<<grid, blk, 0, stream>>>(
            hc[2], HB, hc[0],
            wt + 3 * 73728, bs[3], hp[3], cs[3], hc[3], (t == 7) ? out : nullptr, 2);

        for (int l = 0; l < 4; ++l) { bf16* tmp = hp[l]; hp[l] = hc[l]; hc[l] = tmp; }
    }
}

// Round 7
// 1243.367 us; speedup vs baseline: 2.8504x; 1.8567x over previous
//
#include <hip/hip_runtime.h>

#define HH 128
#define WW 128

typedef __bf16 bf16;
typedef bf16 bf16x8 __attribute__((ext_vector_type(8)));
typedef float f32x4 __attribute__((ext_vector_type(4)));

__device__ __forceinline__ float hsig(float x) {
    return fminf(fmaxf(fmaf(0.2f, x, 0.5f), 0.f), 1.f);
}
__device__ __forceinline__ float ftanh(float x) {
    const float u = __expf(2.f * fminf(x, 40.f));
    return (u - 1.f) * __builtin_amdgcn_rcpf(u + 1.f);
}

// ---- one-time weight prep: fp32 [tap][ci][cout] -> bf16 Wt[l][tap][cout][ci64]
// ci64: x cins at [0,CX), h cins at [CX,CX+32), zero pad to 64. (CX=16 for l=0)
__global__ void prep_weights(const float* __restrict__ Wx0, const float* __restrict__ Wh0,
                             const float* __restrict__ Wx1, const float* __restrict__ Wh1,
                             const float* __restrict__ Wx2, const float* __restrict__ Wh2,
                             const float* __restrict__ Wx3, const float* __restrict__ Wh3,
                             bf16* __restrict__ Wt)
{
    int idx = blockIdx.x * 256 + threadIdx.x;      // 4*9*128*64 = 294912
    if (idx >= 4 * 9 * 128 * 64) return;
    const int l = idx / 73728;
    int r = idx - l * 73728;
    const int tap = r / (128 * 64);
    r -= tap * 128 * 64;
    const int co = r >> 6;
    const int ci = r & 63;
    const int CX = (l == 0) ? 16 : 32;
    const float* Wx = (l == 0) ? Wx0 : (l == 1) ? Wx1 : (l == 2) ? Wx2 : Wx3;
    const float* Wh = (l == 0) ? Wh0 : (l == 1) ? Wh1 : (l == 2) ? Wh2 : Wh3;
    float v = 0.f;
    if (ci < CX)           v = Wx[((size_t)tap * CX + ci) * 128 + co];
    else if (ci < CX + 32) v = Wh[((size_t)tap * 32 + (ci - CX)) * 128 + co];
    Wt[(size_t)l * 73728 + ((size_t)tap * 128 + co) * 64 + ci] = (bf16)v;
}

constexpr int ST = 72;   // ci stride (elems) in LDS halo

// One ConvLSTM step via implicit-GEMM MFMA.
// Block: 16(w) x 8(h) tile x batch; 2 waves; wave wv owns rows 4wv..4wv+3
// (M=64 per wave -> 64 MFMA per tap amortize the 16 B-loads per tap).
// Layouts: h [B,H,W,32] bf16, c [B,H,W,32] fp32 (proven R4 scheme).
template<int CINX, bool XF32>
__global__ __launch_bounds__(128, 2)
void lstm_step(const void* __restrict__ xin_, size_t xbs,
               const bf16* __restrict__ res,
               const bf16* __restrict__ Wt,
               const float* __restrict__ bias,
               const bf16* __restrict__ hprev,
               float* __restrict__ cst,
               bf16* __restrict__ hout,
               float* __restrict__ outf,
               const int mode)   // 0 raw, 1 relu(x), 2 relu(x+res)
{
    __shared__ bf16 sact[180 * ST];        // halo 10y x 18x pixels, 64 ci each

    const int tid = threadIdx.x;
    const int bx = blockIdx.x, by = blockIdx.y, bb = blockIdx.z;

    // ---- stage halo (zeros OOB / pad), bf16, [pix][ci] ----
    for (int i = tid; i < 180 * 8; i += 128) {
        const int pix = i >> 3, g = i & 7;           // g: 8-ci chunk
        const int hy = pix / 18, hx = pix - hy * 18;
        const int sy = by * 8 - 1 + hy, sx = bx * 16 - 1 + hx;
        const bool inb = ((unsigned)sy < HH) && ((unsigned)sx < WW);
        float v[8];
        #pragma unroll
        for (int j = 0; j < 8; ++j) v[j] = 0.f;
        if (inb) {
            const size_t poff = (size_t)sy * WW + sx;
            if (g * 8 < CINX) {                       // x part
                if constexpr (XF32) {
                    const float* xp = (const float*)xin_ + (size_t)bb * xbs + poff * CINX + g * 8;
                    const f32x4 a = *(const f32x4*)xp;
                    const f32x4 b = *(const f32x4*)(xp + 4);
                    v[0] = a.x; v[1] = a.y; v[2] = a.z; v[3] = a.w;
                    v[4] = b.x; v[5] = b.y; v[6] = b.z; v[7] = b.w;
                } else {
                    const bf16* xp = (const bf16*)xin_ + (size_t)bb * xbs + poff * CINX + g * 8;
                    const bf16x8 a = *(const bf16x8*)xp;
                    #pragma unroll
                    for (int j = 0; j < 8; ++j) v[j] = (float)a[j];
                    if (mode == 2) {
                        const bf16x8 rr = *(const bf16x8*)(res + ((size_t)bb * HH * WW + poff) * 32 + g * 8);
                        #pragma unroll
                        for (int j = 0; j < 8; ++j) v[j] += (float)rr[j];
                    }
                    if (mode != 0) {
                        #pragma unroll
                        for (int j = 0; j < 8; ++j) v[j] = fmaxf(v[j], 0.f);
                    }
                }
            } else if (g * 8 < CINX + 32) {           // h part
                const bf16* hp = hprev + ((size_t)bb * HH * WW + poff) * 32 + (g * 8 - CINX);
                const bf16x8 a = *(const bf16x8*)hp;
                #pragma unroll
                for (int j = 0; j < 8; ++j) v[j] = (float)a[j];
            }
        }
        bf16x8 w;
        #pragma unroll
        for (int j = 0; j < 8; ++j) w[j] = (bf16)v[j];
        *(bf16x8*)(&sact[pix * ST + g * 8]) = w;
    }
    __syncthreads();

    const int lane = tid & 63;
    const int wv   = tid >> 6;        // wave id (0,1): rows 4wv..4wv+3
    const int col  = lane & 15;       // A row (x) / C col (cout%16) / B col
    const int krow = lane >> 4;       // k-slice / C row block

    f32x4 acc[4][8];                  // [mt = row][nb = cout16-block]
    #pragma unroll
    for (int nb = 0; nb < 8; ++nb) {
        const float bv = bias[nb * 16 + col];
        #pragma unroll
        for (int mt = 0; mt < 4; ++mt) acc[mt][nb] = (f32x4){bv, bv, bv, bv};
    }

    const bf16* __restrict__ wb0 = Wt + (size_t)col * 64 + krow * 8;

    // ---- 9-tap loop: per tap 8 ds_read (A) + 16 global b128 (B) + 64 MFMA ----
    #pragma unroll 1
    for (int tap = 0; tap < 9; ++tap) {
        const int dy = tap / 3, dx = tap - dy * 3;
        const int r0 = (wv * 4 + dy) * 18 + col + dx;
        bf16x8 A[4][2];
        #pragma unroll
        for (int mt = 0; mt < 4; ++mt) {
            A[mt][0] = *(const bf16x8*)(&sact[(r0 + mt * 18) * ST + krow * 8]);
            A[mt][1] = *(const bf16x8*)(&sact[(r0 + mt * 18) * ST + 32 + krow * 8]);
        }
        const bf16* wt = wb0 + (size_t)tap * 8192;     // 128*64
        #pragma unroll
        for (int kb = 0; kb < 2; ++kb) {
            bf16x8 B[8];
            #pragma unroll
            for (int nb = 0; nb < 8; ++nb)
                B[nb] = *(const bf16x8*)(wt + nb * 1024 + kb * 32);
            #pragma unroll
            for (int mt = 0; mt < 4; ++mt)
                #pragma unroll
                for (int nb = 0; nb < 8; ++nb)
                    acc[mt][nb] = __builtin_amdgcn_mfma_f32_16x16x32_bf16(
                        A[mt][kb], B[nb], acc[mt][nb], 0, 0, 0);
        }
    }

    // ---- lane-local LSTM pointwise ([B,H,W,32] scalar ld/st, L2/L3-hot) ----
    // z(y, x=x0+j, cout=nb*16+col); gate = nb>>1, filter f = (nb&1)*16+col
    const int x0 = bx * 16 + krow * 4;
    #pragma unroll
    for (int mt = 0; mt < 4; ++mt) {
        const int gy = by * 8 + wv * 4 + mt;
        #pragma unroll
        for (int j = 0; j < 4; ++j) {
            const size_t pb = (((size_t)bb * HH + gy) * WW + (x0 + j)) * 32;
            #pragma unroll
            for (int h2 = 0; h2 < 2; ++h2) {
                const int f = h2 * 16 + col;
                const float zi = acc[mt][0 + h2][j];
                const float zf = acc[mt][2 + h2][j];
                const float zg = acc[mt][4 + h2][j];
                const float zo = acc[mt][6 + h2][j];
                const float cold = cst[pb + f];
                const float ig = hsig(zi), fg = hsig(zf);
                const float gg = ftanh(zg), og = hsig(zo);
                const float cn = fmaf(fg, cold, ig * gg);
                cst[pb + f] = cn;
                const float hn = og * ftanh(cn);
                if (outf) outf[pb + f] = hn;
                else      hout[pb + f] = (bf16)hn;
            }
        }
    }
}

extern "C" void kernel_launch(void* const* d_in, const int* in_sizes, int n_in,
                              void* d_out, int out_size, void* d_ws, size_t ws_size,
                              hipStream_t stream) {
    const float* x = (const float*)d_in[0];
    const float* Wx[4] = {(const float*)d_in[1], (const float*)d_in[4],
                          (const float*)d_in[7], (const float*)d_in[10]};
    const float* Wh[4] = {(const float*)d_in[2], (const float*)d_in[5],
                          (const float*)d_in[8], (const float*)d_in[11]};
    const float* bs[4] = {(const float*)d_in[3], (const float*)d_in[6],
                          (const float*)d_in[9], (const float*)d_in[12]};
    float* out = (float*)d_out;

    const size_t S  = (size_t)4 * HH * WW * 32;   // one [B,H,W,32] buffer (elements)
    const size_t HB = (size_t)HH * WW * 32;       // per-batch stride (elements)
    const size_t WT = (size_t)4 * 73728;          // transposed weights (bf16 elems)

    bf16* wt  = (bf16*)d_ws;
    bf16* hb  = wt + WT;
    float* cb = (float*)(hb + 8 * S);
    bf16 *hA[4], *hB[4]; float* cs[4];
    for (int l = 0; l < 4; ++l) {
        hA[l] = hb + (size_t)(2 * l + 0) * S;
        hB[l] = hb + (size_t)(2 * l + 1) * S;
        cs[l] = cb + (size_t)l * S;
    }
    for (int l = 0; l < 4; ++l) {
        hipMemsetAsync(hA[l], 0, S * sizeof(bf16), stream);
        hipMemsetAsync(cs[l], 0, S * sizeof(float), stream);
    }

    prep_weights<<<1152, 256, 0, stream>>>(Wx[0], Wh[0], Wx[1], Wh[1],
                                           Wx[2], Wh[2], Wx[3], Wh[3], wt);

    dim3 grid(WW / 16, HH / 8, 4);
    dim3 blk(128);

    bf16* hp[4] = {hA[0], hA[1], hA[2], hA[3]};
    bf16* hc[4] = {hB[0], hB[1], hB[2], hB[3]};

    for (int t = 0; t < 8; ++t) {
        lstm_step<16, true><<<grid, blk, 0, stream>>>(
            x + (size_t)t * HH * WW * 16, (size_t)8 * HH * WW * 16, nullptr,
            wt + 0 * 73728, bs[0], hp[0], cs[0], hc[0], nullptr, 0);
        lstm_step<32, false><<<grid, blk, 0, stream>>>(
            hc[0], HB, nullptr,
            wt + 1 * 73728, bs[1], hp[1], cs[1], hc[1], nullptr, 0);
        lstm_step<32, false><<<grid, blk, 0, stream>>>(
            hc[1], HB, nullptr,
            wt + 2 * 73728, bs[2], hp[2], cs[2], hc[2], nullptr, 1);
        lstm_step<32, false><<<grid, blk, 0, stream>>>(
            hc[2], HB, hc[0],
            wt + 3 * 73728, bs[3], hp[3], cs[3], hc[3], (t == 7) ? out : nullptr, 2);

        for (int l = 0; l < 4; ++l) { bf16* tmp = hp[l]; hp[l] = hc[l]; hc[l] = tmp; }
    }
}

// Round 8
// 982.876 us; speedup vs baseline: 3.6059x; 1.2650x over previous
//
#include <hip/hip_runtime.h>

#define HH 128
#define WW 128

typedef __bf16 bf16;
typedef bf16 bf16x8 __attribute__((ext_vector_type(8)));
typedef float f32x4 __attribute__((ext_vector_type(4)));

__device__ __forceinline__ float hsig(float x) {
    return fminf(fmaxf(fmaf(0.2f, x, 0.5f), 0.f), 1.f);
}
__device__ __forceinline__ float ftanh(float x) {
    const float u = __expf(2.f * fminf(x, 40.f));
    return (u - 1.f) * __builtin_amdgcn_rcpf(u + 1.f);
}

// ---- one-time weight prep: fp32 [tap][ci][cout] -> bf16 Wt[l][tap][cout][ci64]
// ci64: x cins at [0,CX), h cins at [CX,CX+32), zero pad to 64. (CX=16 for l=0)
__global__ void prep_weights(const float* __restrict__ Wx0, const float* __restrict__ Wh0,
                             const float* __restrict__ Wx1, const float* __restrict__ Wh1,
                             const float* __restrict__ Wx2, const float* __restrict__ Wh2,
                             const float* __restrict__ Wx3, const float* __restrict__ Wh3,
                             bf16* __restrict__ Wt)
{
    int idx = blockIdx.x * 256 + threadIdx.x;      // 4*9*128*64 = 294912
    if (idx >= 4 * 9 * 128 * 64) return;
    const int l = idx / 73728;
    int r = idx - l * 73728;
    const int tap = r / (128 * 64);
    r -= tap * 128 * 64;
    const int co = r >> 6;
    const int ci = r & 63;
    const int CX = (l == 0) ? 16 : 32;
    const float* Wx = (l == 0) ? Wx0 : (l == 1) ? Wx1 : (l == 2) ? Wx2 : Wx3;
    const float* Wh = (l == 0) ? Wh0 : (l == 1) ? Wh1 : (l == 2) ? Wh2 : Wh3;
    float v = 0.f;
    if (ci < CX)           v = Wx[((size_t)tap * CX + ci) * 128 + co];
    else if (ci < CX + 32) v = Wh[((size_t)tap * 32 + (ci - CX)) * 128 + co];
    Wt[(size_t)l * 73728 + ((size_t)tap * 128 + co) * 64 + ci] = (bf16)v;
}

constexpr int ST = 72;   // ci stride (elems) in LDS halo

// One ConvLSTM step via implicit-GEMM MFMA.
// Block: 16(w) x 4(h) tile x batch; 2 waves. Each wave: M=64 (whole tile),
// couts split by nb PARITY p: nb in {p, p+2, p+4, p+6} -> filters p*16..p*16+15
// of ALL 4 gates (epilogue lane-local). A and B pipelined one tap ahead.
template<int CINX, bool XF32>
__global__ __launch_bounds__(128, 2)
void lstm_step(const void* __restrict__ xin_, size_t xbs,
               const bf16* __restrict__ res,
               const bf16* __restrict__ Wt,
               const float* __restrict__ bias,
               const bf16* __restrict__ hprev,
               float* __restrict__ cst,
               bf16* __restrict__ hout,
               float* __restrict__ outf,
               const int mode)   // 0 raw, 1 relu(x), 2 relu(x+res)
{
    __shared__ bf16 sact[108 * ST];        // halo 6y x 18x pixels, 64 ci each

    const int tid = threadIdx.x;
    const int bx = blockIdx.x, by = blockIdx.y, bb = blockIdx.z;

    // ---- stage halo (zeros OOB / pad), bf16, [pix][ci] ----
    for (int i = tid; i < 108 * 8; i += 128) {
        const int pix = i >> 3, g = i & 7;           // g: 8-ci chunk
        const int hy = pix / 18, hx = pix - hy * 18;
        const int sy = by * 4 - 1 + hy, sx = bx * 16 - 1 + hx;
        const bool inb = ((unsigned)sy < HH) && ((unsigned)sx < WW);
        float v[8];
        #pragma unroll
        for (int j = 0; j < 8; ++j) v[j] = 0.f;
        if (inb) {
            const size_t poff = (size_t)sy * WW + sx;
            if (g * 8 < CINX) {                       // x part
                if constexpr (XF32) {
                    const float* xp = (const float*)xin_ + (size_t)bb * xbs + poff * CINX + g * 8;
                    const f32x4 a = *(const f32x4*)xp;
                    const f32x4 b = *(const f32x4*)(xp + 4);
                    v[0] = a.x; v[1] = a.y; v[2] = a.z; v[3] = a.w;
                    v[4] = b.x; v[5] = b.y; v[6] = b.z; v[7] = b.w;
                } else {
                    const bf16* xp = (const bf16*)xin_ + (size_t)bb * xbs + poff * CINX + g * 8;
                    const bf16x8 a = *(const bf16x8*)xp;
                    #pragma unroll
                    for (int j = 0; j < 8; ++j) v[j] = (float)a[j];
                    if (mode == 2) {
                        const bf16x8 rr = *(const bf16x8*)(res + ((size_t)bb * HH * WW + poff) * 32 + g * 8);
                        #pragma unroll
                        for (int j = 0; j < 8; ++j) v[j] += (float)rr[j];
                    }
                    if (mode != 0) {
                        #pragma unroll
                        for (int j = 0; j < 8; ++j) v[j] = fmaxf(v[j], 0.f);
                    }
                }
            } else if (g * 8 < CINX + 32) {           // h part
                const bf16* hp = hprev + ((size_t)bb * HH * WW + poff) * 32 + (g * 8 - CINX);
                const bf16x8 a = *(const bf16x8*)hp;
                #pragma unroll
                for (int j = 0; j < 8; ++j) v[j] = (float)a[j];
            }
        }
        bf16x8 w;
        #pragma unroll
        for (int j = 0; j < 8; ++j) w[j] = (bf16)v[j];
        *(bf16x8*)(&sact[pix * ST + g * 8]) = w;
    }
    __syncthreads();

    const int lane = tid & 63;
    const int p    = tid >> 6;        // wave parity: nb = p + 2q
    const int col  = lane & 15;       // A row (x) / C col (cout%16) / B col
    const int krow = lane >> 4;       // k-slice / C row block

    f32x4 acc[4][4];                  // [mt = row][q: gate]
    #pragma unroll
    for (int q = 0; q < 4; ++q) {
        const float bv = bias[(p + 2 * q) * 16 + col];
        #pragma unroll
        for (int mt = 0; mt < 4; ++mt) acc[mt][q] = (f32x4){bv, bv, bv, bv};
    }

    const bf16* __restrict__ wb0 = Wt + (size_t)(p * 16 + col) * 64 + krow * 8;
    const int abase = col * ST + krow * 8;

    // pipelined A/B tap buffers (named, static indexing only)
    bf16x8 A0[4][2], A1[4][2], B0[2][4], B1[2][4];

#define LOAD_A(Abuf, tap) do {                                              \
        const int dy_ = (tap) / 3, dx_ = (tap) - dy_ * 3;                   \
        const int o_ = abase + (dy_ * 18 + dx_) * ST;                       \
        _Pragma("unroll")                                                   \
        for (int mt_ = 0; mt_ < 4; ++mt_) {                                 \
            Abuf[mt_][0] = *(const bf16x8*)(&sact[o_ + mt_ * 18 * ST]);      \
            Abuf[mt_][1] = *(const bf16x8*)(&sact[o_ + mt_ * 18 * ST + 32]); \
        }                                                                   \
    } while (0)

#define LOAD_B(Bbuf, tap) do {                                              \
        const bf16* wt_ = wb0 + (size_t)(tap) * 8192;                       \
        _Pragma("unroll")                                                   \
        for (int q_ = 0; q_ < 4; ++q_) {                                    \
            Bbuf[0][q_] = *(const bf16x8*)(wt_ + q_ * 2048);                \
            Bbuf[1][q_] = *(const bf16x8*)(wt_ + q_ * 2048 + 32);           \
        }                                                                   \
    } while (0)

#define MFMA_TAP(Abuf, Bbuf) do {                                           \
        _Pragma("unroll")                                                   \
        for (int kb_ = 0; kb_ < 2; ++kb_)                                   \
            _Pragma("unroll")                                               \
            for (int mt_ = 0; mt_ < 4; ++mt_)                               \
                _Pragma("unroll")                                           \
                for (int q_ = 0; q_ < 4; ++q_)                              \
                    acc[mt_][q_] = __builtin_amdgcn_mfma_f32_16x16x32_bf16( \
                        Abuf[mt_][kb_], Bbuf[kb_][q_], acc[mt_][q_], 0, 0, 0); \
    } while (0)

    LOAD_A(A0, 0); LOAD_B(B0, 0);
    #pragma unroll 1
    for (int k = 0; k < 4; ++k) {
        const int t1 = 2 * k + 1, t2 = 2 * k + 2;
        LOAD_A(A1, t1); LOAD_B(B1, t1);
        MFMA_TAP(A0, B0);
        LOAD_A(A0, t2); LOAD_B(B0, t2);
        MFMA_TAP(A1, B1);
    }
    MFMA_TAP(A0, B0);   // tap 8

    // ---- lane-local LSTM pointwise ([B,H,W,32] scalar ld/st, L2/L3-hot) ----
    // acc[mt][q][j]: y = by*4+mt, x = bx*16+krow*4+j, gate q, filter f = p*16+col
    const int x0 = bx * 16 + krow * 4;
    const int f  = p * 16 + col;
    #pragma unroll
    for (int mt = 0; mt < 4; ++mt) {
        const int gy = by * 4 + mt;
        #pragma unroll
        for (int j = 0; j < 4; ++j) {
            const size_t pb = (((size_t)bb * HH + gy) * WW + (x0 + j)) * 32 + f;
            const float zi = acc[mt][0][j];
            const float zf = acc[mt][1][j];
            const float zg = acc[mt][2][j];
            const float zo = acc[mt][3][j];
            const float cold = cst[pb];
            const float ig = hsig(zi), fg = hsig(zf);
            const float gg = ftanh(zg), og = hsig(zo);
            const float cn = fmaf(fg, cold, ig * gg);
            cst[pb] = cn;
            const float hn = og * ftanh(cn);
            if (outf) outf[pb] = hn;
            else      hout[pb] = (bf16)hn;
        }
    }
#undef LOAD_A
#undef LOAD_B
#undef MFMA_TAP
}

extern "C" void kernel_launch(void* const* d_in, const int* in_sizes, int n_in,
                              void* d_out, int out_size, void* d_ws, size_t ws_size,
                              hipStream_t stream) {
    const float* x = (const float*)d_in[0];
    const float* Wx[4] = {(const float*)d_in[1], (const float*)d_in[4],
                          (const float*)d_in[7], (const float*)d_in[10]};
    const float* Wh[4] = {(const float*)d_in[2], (const float*)d_in[5],
                          (const float*)d_in[8], (const float*)d_in[11]};
    const float* bs[4] = {(const float*)d_in[3], (const float*)d_in[6],
                          (const float*)d_in[9], (const float*)d_in[12]};
    float* out = (float*)d_out;

    const size_t S  = (size_t)4 * HH * WW * 32;   // one [B,H,W,32] buffer (elements)
    const size_t HB = (size_t)HH * WW * 32;       // per-batch stride (elements)
    const size_t WT = (size_t)4 * 73728;          // transposed weights (bf16 elems)

    bf16* wt  = (bf16*)d_ws;
    bf16* hb  = wt + WT;
    float* cb = (float*)(hb + 8 * S);
    bf16 *hA[4], *hB[4]; float* cs[4];
    for (int l = 0; l < 4; ++l) {
        hA[l] = hb + (size_t)(2 * l + 0) * S;
        hB[l] = hb + (size_t)(2 * l + 1) * S;
        cs[l] = cb + (size_t)l * S;
    }
    for (int l = 0; l < 4; ++l) {
        hipMemsetAsync(hA[l], 0, S * sizeof(bf16), stream);
        hipMemsetAsync(cs[l], 0, S * sizeof(float), stream);
    }

    prep_weights<<<1152, 256, 0, stream>>>(Wx[0], Wh[0], Wx[1], Wh[1],
                                           Wx[2], Wh[2], Wx[3], Wh[3], wt);

    dim3 grid(WW / 16, HH / 4, 4);
    dim3 blk(128);

    bf16* hp[4] = {hA[0], hA[1], hA[2], hA[3]};
    bf16* hc[4] = {hB[0], hB[1], hB[2], hB[3]};

    for (int t = 0; t < 8; ++t) {
        lstm_step<16, true><<<grid, blk, 0, stream>>>(
            x + (size_t)t * HH * WW * 16, (size_t)8 * HH * WW * 16, nullptr,
            wt + 0 * 73728, bs[0], hp[0], cs[0], hc[0], nullptr, 0);
        lstm_step<32, false><<<grid, blk, 0, stream>>>(
            hc[0], HB, nullptr,
            wt + 1 * 73728, bs[1], hp[1], cs[1], hc[1], nullptr, 0);
        lstm_step<32, false><<<grid, blk, 0, stream>>>(
            hc[1], HB, nullptr,
            wt + 2 * 73728, bs[2], hp[2], cs[2], hc[2], nullptr, 1);
        lstm_step<32, false><<<grid, blk, 0, stream>>>(
            hc[2], HB, hc[0],
            wt + 3 * 73728, bs[3], hp[3], cs[3], hc[3], (t == 7) ? out : nullptr, 2);

        for (int l = 0; l < 4; ++l) { bf16* tmp = hp[l]; hp[l] = hc[l]; hc[l] = tmp; }
    }
}

// Round 9
// 931.139 us; speedup vs baseline: 3.8063x; 1.0556x over previous
//
#include <hip/hip_runtime.h>

#define HH 128
#define WW 128

typedef __bf16 bf16;
typedef bf16 bf16x8 __attribute__((ext_vector_type(8)));
typedef float f32x4 __attribute__((ext_vector_type(4)));

__device__ __forceinline__ float hsig(float x) {
    return fminf(fmaxf(fmaf(0.2f, x, 0.5f), 0.f), 1.f);
}
__device__ __forceinline__ float ftanh(float x) {
    const float u = __expf(2.f * fminf(x, 40.f));
    return (u - 1.f) * __builtin_amdgcn_rcpf(u + 1.f);
}

// ---- one-time weight prep: fp32 [tap][ci][cout] -> bf16 Wt[l][tap][cout][ci64]
// ci64: x cins at [0,CX), h cins at [CX,CX+32), zero pad to 64. (CX=16 for l=0)
__global__ void prep_weights(const float* __restrict__ Wx0, const float* __restrict__ Wh0,
                             const float* __restrict__ Wx1, const float* __restrict__ Wh1,
                             const float* __restrict__ Wx2, const float* __restrict__ Wh2,
                             const float* __restrict__ Wx3, const float* __restrict__ Wh3,
                             bf16* __restrict__ Wt)
{
    int idx = blockIdx.x * 256 + threadIdx.x;      // 4*9*128*64 = 294912
    if (idx >= 4 * 9 * 128 * 64) return;
    const int l = idx / 73728;
    int r = idx - l * 73728;
    const int tap = r / (128 * 64);
    r -= tap * 128 * 64;
    const int co = r >> 6;
    const int ci = r & 63;
    const int CX = (l == 0) ? 16 : 32;
    const float* Wx = (l == 0) ? Wx0 : (l == 1) ? Wx1 : (l == 2) ? Wx2 : Wx3;
    const float* Wh = (l == 0) ? Wh0 : (l == 1) ? Wh1 : (l == 2) ? Wh2 : Wh3;
    float v = 0.f;
    if (ci < CX)           v = Wx[((size_t)tap * CX + ci) * 128 + co];
    else if (ci < CX + 32) v = Wh[((size_t)tap * 32 + (ci - CX)) * 128 + co];
    Wt[(size_t)l * 73728 + ((size_t)tap * 128 + co) * 64 + ci] = (bf16)v;
}

constexpr int ST = 72;   // ci stride (elems) in LDS halo

// One ConvLSTM step via implicit-GEMM MFMA.
// Block: 16(w) x 4(h) tile x batch; 2 waves. Each wave: M=64 (whole tile),
// couts split by nb PARITY p: nb in {p, p+2, p+4, p+6} -> filters p*16..p*16+15
// of ALL 4 gates (epilogue lane-local). A and B pipelined one tap ahead.
// FIRST: t=0 step -> hprev treated as zero (not read), c_old = 0 (not read).
template<int CINX, bool XF32, bool FIRST>
__global__ __launch_bounds__(128, 2)
void lstm_step(const void* __restrict__ xin_, size_t xbs,
               const bf16* __restrict__ res,
               const bf16* __restrict__ Wt,
               const float* __restrict__ bias,
               const bf16* __restrict__ hprev,
               float* __restrict__ cst,
               bf16* __restrict__ hout,
               float* __restrict__ outf,
               const int mode)   // 0 raw, 1 relu(x), 2 relu(x+res)
{
    __shared__ bf16 sact[108 * ST];        // halo 6y x 18x pixels, 64 ci each

    const int tid = threadIdx.x;
    const int bx = blockIdx.x, by = blockIdx.y, bb = blockIdx.z;

    // ---- stage halo (zeros OOB / pad), bf16, [pix][ci] ----
    for (int i = tid; i < 108 * 8; i += 128) {
        const int pix = i >> 3, g = i & 7;           // g: 8-ci chunk
        const int hy = pix / 18, hx = pix - hy * 18;
        const int sy = by * 4 - 1 + hy, sx = bx * 16 - 1 + hx;
        const bool inb = ((unsigned)sy < HH) && ((unsigned)sx < WW);
        float v[8];
        #pragma unroll
        for (int j = 0; j < 8; ++j) v[j] = 0.f;
        if (inb) {
            const size_t poff = (size_t)sy * WW + sx;
            if (g * 8 < CINX) {                       // x part
                if constexpr (XF32) {
                    const float* xp = (const float*)xin_ + (size_t)bb * xbs + poff * CINX + g * 8;
                    const f32x4 a = *(const f32x4*)xp;
                    const f32x4 b = *(const f32x4*)(xp + 4);
                    v[0] = a.x; v[1] = a.y; v[2] = a.z; v[3] = a.w;
                    v[4] = b.x; v[5] = b.y; v[6] = b.z; v[7] = b.w;
                } else {
                    const bf16* xp = (const bf16*)xin_ + (size_t)bb * xbs + poff * CINX + g * 8;
                    const bf16x8 a = *(const bf16x8*)xp;
                    #pragma unroll
                    for (int j = 0; j < 8; ++j) v[j] = (float)a[j];
                    if (mode == 2) {
                        const bf16x8 rr = *(const bf16x8*)(res + ((size_t)bb * HH * WW + poff) * 32 + g * 8);
                        #pragma unroll
                        for (int j = 0; j < 8; ++j) v[j] += (float)rr[j];
                    }
                    if (mode != 0) {
                        #pragma unroll
                        for (int j = 0; j < 8; ++j) v[j] = fmaxf(v[j], 0.f);
                    }
                }
            } else if (g * 8 < CINX + 32) {           // h part (zero when FIRST)
                if constexpr (!FIRST) {
                    const bf16* hp = hprev + ((size_t)bb * HH * WW + poff) * 32 + (g * 8 - CINX);
                    const bf16x8 a = *(const bf16x8*)hp;
                    #pragma unroll
                    for (int j = 0; j < 8; ++j) v[j] = (float)a[j];
                }
            }
        }
        bf16x8 w;
        #pragma unroll
        for (int j = 0; j < 8; ++j) w[j] = (bf16)v[j];
        *(bf16x8*)(&sact[pix * ST + g * 8]) = w;
    }
    __syncthreads();

    const int lane = tid & 63;
    const int p    = tid >> 6;        // wave parity: nb = p + 2q
    const int col  = lane & 15;       // A row (x) / C col (cout%16) / B col
    const int krow = lane >> 4;       // k-slice / C row block

    f32x4 acc[4][4];                  // [mt = row][q: gate]
    #pragma unroll
    for (int q = 0; q < 4; ++q) {
        const float bv = bias[(p + 2 * q) * 16 + col];
        #pragma unroll
        for (int mt = 0; mt < 4; ++mt) acc[mt][q] = (f32x4){bv, bv, bv, bv};
    }

    const bf16* __restrict__ wb0 = Wt + (size_t)(p * 16 + col) * 64 + krow * 8;
    const int abase = col * ST + krow * 8;

    // pipelined A/B tap buffers (named, static indexing only)
    bf16x8 A0[4][2], A1[4][2], B0[2][4], B1[2][4];

#define LOAD_A(Abuf, tap) do {                                              \
        const int dy_ = (tap) / 3, dx_ = (tap) - dy_ * 3;                   \
        const int o_ = abase + (dy_ * 18 + dx_) * ST;                       \
        _Pragma("unroll")                                                   \
        for (int mt_ = 0; mt_ < 4; ++mt_) {                                 \
            Abuf[mt_][0] = *(const bf16x8*)(&sact[o_ + mt_ * 18 * ST]);      \
            Abuf[mt_][1] = *(const bf16x8*)(&sact[o_ + mt_ * 18 * ST + 32]); \
        }                                                                   \
    } while (0)

#define LOAD_B(Bbuf, tap) do {                                              \
        const bf16* wt_ = wb0 + (size_t)(tap) * 8192;                       \
        _Pragma("unroll")                                                   \
        for (int q_ = 0; q_ < 4; ++q_) {                                    \
            Bbuf[0][q_] = *(const bf16x8*)(wt_ + q_ * 2048);                \
            Bbuf[1][q_] = *(const bf16x8*)(wt_ + q_ * 2048 + 32);           \
        }                                                                   \
    } while (0)

#define MFMA_TAP(Abuf, Bbuf) do {                                           \
        _Pragma("unroll")                                                   \
        for (int kb_ = 0; kb_ < 2; ++kb_)                                   \
            _Pragma("unroll")                                               \
            for (int mt_ = 0; mt_ < 4; ++mt_)                               \
                _Pragma("unroll")                                           \
                for (int q_ = 0; q_ < 4; ++q_)                              \
                    acc[mt_][q_] = __builtin_amdgcn_mfma_f32_16x16x32_bf16( \
                        Abuf[mt_][kb_], Bbuf[kb_][q_], acc[mt_][q_], 0, 0, 0); \
    } while (0)

    LOAD_A(A0, 0); LOAD_B(B0, 0);
    #pragma unroll 1
    for (int k = 0; k < 4; ++k) {
        const int t1 = 2 * k + 1, t2 = 2 * k + 2;
        LOAD_A(A1, t1); LOAD_B(B1, t1);
        MFMA_TAP(A0, B0);
        LOAD_A(A0, t2); LOAD_B(B0, t2);
        MFMA_TAP(A1, B1);
    }
    MFMA_TAP(A0, B0);   // tap 8

    // ---- lane-local LSTM pointwise ([B,H,W,32] scalar ld/st, L2/L3-hot) ----
    // acc[mt][q][j]: y = by*4+mt, x = bx*16+krow*4+j, gate q, filter f = p*16+col
    const int x0 = bx * 16 + krow * 4;
    const int f  = p * 16 + col;
    #pragma unroll
    for (int mt = 0; mt < 4; ++mt) {
        const int gy = by * 4 + mt;
        #pragma unroll
        for (int j = 0; j < 4; ++j) {
            const size_t pb = (((size_t)bb * HH + gy) * WW + (x0 + j)) * 32 + f;
            const float zi = acc[mt][0][j];
            const float zf = acc[mt][1][j];
            const float zg = acc[mt][2][j];
            const float zo = acc[mt][3][j];
            const float cold = FIRST ? 0.f : cst[pb];
            const float ig = hsig(zi), fg = hsig(zf);
            const float gg = ftanh(zg), og = hsig(zo);
            const float cn = fmaf(fg, cold, ig * gg);
            const float hn = og * ftanh(cn);
            if (outf) {
                outf[pb] = hn;           // final step: c never read again
            } else {
                cst[pb] = cn;
                hout[pb] = (bf16)hn;
            }
        }
    }
#undef LOAD_A
#undef LOAD_B
#undef MFMA_TAP
}

extern "C" void kernel_launch(void* const* d_in, const int* in_sizes, int n_in,
                              void* d_out, int out_size, void* d_ws, size_t ws_size,
                              hipStream_t stream) {
    const float* x = (const float*)d_in[0];
    const float* Wx[4] = {(const float*)d_in[1], (const float*)d_in[4],
                          (const float*)d_in[7], (const float*)d_in[10]};
    const float* Wh[4] = {(const float*)d_in[2], (const float*)d_in[5],
                          (const float*)d_in[8], (const float*)d_in[11]};
    const float* bs[4] = {(const float*)d_in[3], (const float*)d_in[6],
                          (const float*)d_in[9], (const float*)d_in[12]};
    float* out = (float*)d_out;

    const size_t S  = (size_t)4 * HH * WW * 32;   // one [B,H,W,32] buffer (elements)
    const size_t HB = (size_t)HH * WW * 32;       // per-batch stride (elements)
    const size_t WT = (size_t)4 * 73728;          // transposed weights (bf16 elems)

    bf16* wt  = (bf16*)d_ws;
    bf16* hb  = wt + WT;
    float* cb = (float*)(hb + 8 * S);
    bf16 *hA[4], *hB[4]; float* cs[4];
    for (int l = 0; l < 4; ++l) {
        hA[l] = hb + (size_t)(2 * l + 0) * S;
        hB[l] = hb + (size_t)(2 * l + 1) * S;
        cs[l] = cb + (size_t)l * S;
    }
    // NO memsets: t=0 launches use FIRST=true (never read hprev / cst).

    prep_weights<<<1152, 256, 0, stream>>>(Wx[0], Wh[0], Wx[1], Wh[1],
                                           Wx[2], Wh[2], Wx[3], Wh[3], wt);

    dim3 grid(WW / 16, HH / 4, 4);
    dim3 blk(128);

    bf16* hp[4] = {hA[0], hA[1], hA[2], hA[3]};
    bf16* hc[4] = {hB[0], hB[1], hB[2], hB[3]};

    const size_t XT = (size_t)HH * WW * 16;   // per-t x stride
    const size_t XB = (size_t)8 * HH * WW * 16;

    // t = 0 (FIRST: h_prev = 0, c_old = 0)
    lstm_step<16, true,  true><<<grid, blk, 0, stream>>>(
        x, XB, nullptr, wt + 0 * 73728, bs[0], nullptr, cs[0], hc[0], nullptr, 0);
    lstm_step<32, false, true><<<grid, blk, 0, stream>>>(
        hc[0], HB, nullptr, wt + 1 * 73728, bs[1], nullptr, cs[1], hc[1], nullptr, 0);
    lstm_step<32, false, true><<<grid, blk, 0, stream>>>(
        hc[1], HB, nullptr, wt + 2 * 73728, bs[2], nullptr, cs[2], hc[2], nullptr, 1);
    lstm_step<32, false, true><<<grid, blk, 0, stream>>>(
        hc[2], HB, hc[0],  wt + 3 * 73728, bs[3], nullptr, cs[3], hc[3], nullptr, 2);
    for (int l = 0; l < 4; ++l) { bf16* tmp = hp[l]; hp[l] = hc[l]; hc[l] = tmp; }

    for (int t = 1; t < 8; ++t) {
        lstm_step<16, true,  false><<<grid, blk, 0, stream>>>(
            x + (size_t)t * XT, XB, nullptr,
            wt + 0 * 73728, bs[0], hp[0], cs[0], hc[0], nullptr, 0);
        lstm_step<32, false, false><<<grid, blk, 0, stream>>>(
            hc[0], HB, nullptr,
            wt + 1 * 73728, bs[1], hp[1], cs[1], hc[1], nullptr, 0);
        lstm_step<32, false, false><<<grid, blk, 0, stream>>>(
            hc[1], HB, nullptr,
            wt + 2 * 73728, bs[2], hp[2], cs[2], hc[2], nullptr, 1);
        lstm_step<32, false, false><<<grid, blk, 0, stream>>>(
            hc[2], HB, hc[0],
            wt + 3 * 73728, bs[3], hp[3], cs[3], hc[3], (t == 7) ? out : nullptr, 2);

        for (int l = 0; l < 4; ++l) { bf16* tmp = hp[l]; hp[l] = hc[l]; hc[l] = tmp; }
    }
}

// Round 11
// 841.522 us; speedup vs baseline: 4.2116x; 1.1065x over previous
//
#include <hip/hip_runtime.h>

#define HH 128
#define WW 128

typedef __bf16 bf16;
typedef bf16 bf16x8 __attribute__((ext_vector_type(8)));
typedef float f32x4 __attribute__((ext_vector_type(4)));

__device__ __forceinline__ float hsig(float x) {
    return fminf(fmaxf(fmaf(0.2f, x, 0.5f), 0.f), 1.f);
}
__device__ __forceinline__ float ftanh(float x) {
    const float u = __expf(2.f * fminf(x, 40.f));
    return (u - 1.f) * __builtin_amdgcn_rcpf(u + 1.f);
}

// ---- one-time weight prep: fp32 [tap][ci][cout] -> bf16 Wt[l][tap][cout][ci64]
// Unified ci64 layout for ALL layers: input cins at [0,CX) (CX=16 for l0, else 32),
// zeros [CX,32), own-h cins at [32,64).
__global__ void prep_weights(const float* __restrict__ Wx0, const float* __restrict__ Wh0,
                             const float* __restrict__ Wx1, const float* __restrict__ Wh1,
                             const float* __restrict__ Wx2, const float* __restrict__ Wh2,
                             const float* __restrict__ Wx3, const float* __restrict__ Wh3,
                             bf16* __restrict__ Wt)
{
    int idx = blockIdx.x * 256 + threadIdx.x;      // 4*9*128*64 = 294912
    if (idx >= 4 * 9 * 128 * 64) return;
    const int l = idx / 73728;
    int r = idx - l * 73728;
    const int tap = r / (128 * 64);
    r -= tap * 128 * 64;
    const int co = r >> 6;
    const int ci = r & 63;
    const int CX = (l == 0) ? 16 : 32;
    const float* Wx = (l == 0) ? Wx0 : (l == 1) ? Wx1 : (l == 2) ? Wx2 : Wx3;
    const float* Wh = (l == 0) ? Wh0 : (l == 1) ? Wh1 : (l == 2) ? Wh2 : Wh3;
    float v = 0.f;
    if (ci < 32) { if (ci < CX) v = Wx[((size_t)tap * CX + ci) * 128 + co]; }
    else          v = Wh[((size_t)tap * 32 + (ci - 32)) * 128 + co];
    Wt[(size_t)l * 73728 + ((size_t)tap * 128 + co) * 64 + ci] = (bf16)v;
}

constexpr int ST = 72;   // ci stride (elems) in LDS halo

// Diagonal-wavefront ConvLSTM stage kernel. One launch covers all stages
// (t, l) with t + l == d (independent of each other). blockIdx.z packs
// {stage s, batch bb}. Per-stage body = proven R8 kernel: 16x4 tile, 2 waves,
// M=64/wave, cout parity split, A/B pipelined one tap ahead, lane-local epilogue.
// h rings: layer0 4-deep (residual read at d+3), layers1-3 2-deep.
__global__ __launch_bounds__(128, 2)
void lstm_stage(const float* __restrict__ x,
                const bf16* __restrict__ Wt,
                const float* __restrict__ b0, const float* __restrict__ b1,
                const float* __restrict__ b2, const float* __restrict__ b3,
                bf16* __restrict__ h0, bf16* __restrict__ h1,
                bf16* __restrict__ h2, bf16* __restrict__ h3,
                float* __restrict__ cbase,
                float* __restrict__ outf,
                const int d, const int lmin)
{
    __shared__ bf16 sact[108 * ST];        // halo 6y x 18x pixels, 64 ci each

    const int tid = threadIdx.x;
    const int bx = blockIdx.x, by = blockIdx.y;
    const int s  = blockIdx.z >> 2, bb = blockIdx.z & 3;
    const int l  = lmin + s;
    const int t  = d - l;

    const size_t S = (size_t)4 * HH * WW * 32;
    bf16* hlbase = (l == 0) ? h0 : (l == 1) ? h1 : (l == 2) ? h2 : h3;
    bf16*       hcur = hlbase + (size_t)((l == 0) ? (t & 3) : (t & 1)) * S;
    const bf16* hprv = hlbase + (size_t)((l == 0) ? ((t + 3) & 3) : ((t + 1) & 1)) * S;
    const bf16* hin  = (l == 1) ? h0 + (size_t)(t & 3) * S
                     : (l == 2) ? h1 + (size_t)(t & 1) * S
                     : (l == 3) ? h2 + (size_t)(t & 1) * S : nullptr;
    const bf16* resp = h0 + (size_t)(t & 3) * S;           // layer0 h at t (l==3)
    const float* bias = (l == 0) ? b0 : (l == 1) ? b1 : (l == 2) ? b2 : b3;
    float* cst = cbase + (size_t)l * S;

    // ---- stage halo (6y x 18x, 64 ci), zeros OOB/pad; branches are l/t-uniform ----
    for (int i = tid; i < 108 * 8; i += 128) {
        const int pix = i >> 3, g = i & 7;
        const int hy = pix / 18, hx = pix - hy * 18;
        const int sy = by * 4 - 1 + hy, sx = bx * 16 - 1 + hx;
        const bool inb = ((unsigned)sy < HH) && ((unsigned)sx < WW);
        float v[8];
        #pragma unroll
        for (int j = 0; j < 8; ++j) v[j] = 0.f;
        if (inb) {
            const size_t poff = (size_t)sy * WW + sx;
            if (g < 4) {                              // input part (ci64 [0,32))
                if (l == 0) {
                    if (g < 2) {                      // x fp32, 16 channels
                        const float* xp = x + ((size_t)(bb * 8 + t) * HH * WW + poff) * 16 + g * 8;
                        const f32x4 a = *(const f32x4*)xp;
                        const f32x4 b = *(const f32x4*)(xp + 4);
                        v[0] = a.x; v[1] = a.y; v[2] = a.z; v[3] = a.w;
                        v[4] = b.x; v[5] = b.y; v[6] = b.z; v[7] = b.w;
                    }                                  // g=2,3: zero pad
                } else {
                    const bf16* ip = hin + ((size_t)bb * HH * WW + poff) * 32 + g * 8;
                    const bf16x8 a = *(const bf16x8*)ip;
                    #pragma unroll
                    for (int j = 0; j < 8; ++j) v[j] = (float)a[j];
                    if (l == 3) {
                        const bf16x8 rr = *(const bf16x8*)(resp + ((size_t)bb * HH * WW + poff) * 32 + g * 8);
                        #pragma unroll
                        for (int j = 0; j < 8; ++j) v[j] += (float)rr[j];
                    }
                    if (l >= 2) {
                        #pragma unroll
                        for (int j = 0; j < 8; ++j) v[j] = fmaxf(v[j], 0.f);
                    }
                }
            } else if (t > 0) {                       // own h_prev (ci64 [32,64))
                const bf16* hp = hprv + ((size_t)bb * HH * WW + poff) * 32 + (g - 4) * 8;
                const bf16x8 a = *(const bf16x8*)hp;
                #pragma unroll
                for (int j = 0; j < 8; ++j) v[j] = (float)a[j];
            }
        }
        bf16x8 w;
        #pragma unroll
        for (int j = 0; j < 8; ++j) w[j] = (bf16)v[j];
        *(bf16x8*)(&sact[pix * ST + g * 8]) = w;
    }
    __syncthreads();

    const int lane = tid & 63;
    const int p    = tid >> 6;        // wave parity: nb = p + 2q
    const int col  = lane & 15;       // A row (x) / C col (cout%16) / B col
    const int krow = lane >> 4;       // k-slice / C row block
    const int abase = col * ST + krow * 8;

    f32x4 acc2[4][4];                 // [mt = row][q = gate]
    #pragma unroll
    for (int q = 0; q < 4; ++q) {
        const float bv = bias[(p + 2 * q) * 16 + col];
        #pragma unroll
        for (int mt = 0; mt < 4; ++mt) acc2[mt][q] = (f32x4){bv, bv, bv, bv};
    }

    const bf16* __restrict__ wb0 = Wt + (size_t)l * 73728 + (size_t)(p * 16 + col) * 64 + krow * 8;

    bf16x8 A0[4][2], A1[4][2], B0[2][4], B1[2][4];

#define LOAD_A(Abuf, tap) do {                                               \
        const int dy_ = (tap) / 3, dx_ = (tap) - dy_ * 3;                    \
        const int o_ = abase + (dy_ * 18 + dx_) * ST;                        \
        _Pragma("unroll")                                                    \
        for (int mt_ = 0; mt_ < 4; ++mt_) {                                  \
            Abuf[mt_][0] = *(const bf16x8*)(&sact[o_ + mt_ * 18 * ST]);       \
            Abuf[mt_][1] = *(const bf16x8*)(&sact[o_ + mt_ * 18 * ST + 32]);  \
        }                                                                    \
    } while (0)

#define LOAD_B(Bbuf, tap) do {                                               \
        const bf16* wt_ = wb0 + (size_t)(tap) * 8192;                        \
        _Pragma("unroll")                                                    \
        for (int q_ = 0; q_ < 4; ++q_) {                                     \
            Bbuf[0][q_] = *(const bf16x8*)(wt_ + q_ * 2048);                 \
            Bbuf[1][q_] = *(const bf16x8*)(wt_ + q_ * 2048 + 32);            \
        }                                                                    \
    } while (0)

#define MFMA_TAP(Abuf, Bbuf) do {                                            \
        _Pragma("unroll")                                                    \
        for (int kb_ = 0; kb_ < 2; ++kb_)                                    \
            _Pragma("unroll")                                                \
            for (int mt_ = 0; mt_ < 4; ++mt_)                                \
                _Pragma("unroll")                                            \
                for (int q_ = 0; q_ < 4; ++q_)                               \
                    acc2[mt_][q_] = __builtin_amdgcn_mfma_f32_16x16x32_bf16( \
                        Abuf[mt_][kb_], Bbuf[kb_][q_], acc2[mt_][q_], 0, 0, 0); \
    } while (0)

    LOAD_A(A0, 0); LOAD_B(B0, 0);
    #pragma unroll 1
    for (int k = 0; k < 4; ++k) {
        const int t1 = 2 * k + 1, t2 = 2 * k + 2;
        LOAD_A(A1, t1); LOAD_B(B1, t1);
        MFMA_TAP(A0, B0);
        LOAD_A(A0, t2); LOAD_B(B0, t2);
        MFMA_TAP(A1, B1);
    }
    MFMA_TAP(A0, B0);   // tap 8

#undef LOAD_A
#undef LOAD_B
#undef MFMA_TAP

    // ---- lane-local LSTM pointwise ([B,H,W,32] scalar ld/st, L2/L3-hot) ----
    const int x0 = bx * 16 + krow * 4;
    const int f  = p * 16 + col;
    #pragma unroll
    for (int mt = 0; mt < 4; ++mt) {
        const int gy = by * 4 + mt;
        #pragma unroll
        for (int j = 0; j < 4; ++j) {
            const size_t pb = (((size_t)bb * HH + gy) * WW + (x0 + j)) * 32 + f;
            const float zi = acc2[mt][0][j];
            const float zf = acc2[mt][1][j];
            const float zg = acc2[mt][2][j];
            const float zo = acc2[mt][3][j];
            const float cold = (t == 0) ? 0.f : cst[pb];
            const float ig = hsig(zi), fg = hsig(zf);
            const float gg = ftanh(zg), og = hsig(zo);
            const float cn = fmaf(fg, cold, ig * gg);
            const float hn = og * ftanh(cn);
            if (t != 7) cst[pb] = cn;                 // c(8) never read
            if (l == 3 && t == 7) outf[pb] = hn;
            else                  hcur[pb] = (bf16)hn;
        }
    }
}

extern "C" void kernel_launch(void* const* d_in, const int* in_sizes, int n_in,
                              void* d_out, int out_size, void* d_ws, size_t ws_size,
                              hipStream_t stream) {
    const float* x = (const float*)d_in[0];
    const float* Wx[4] = {(const float*)d_in[1], (const float*)d_in[4],
                          (const float*)d_in[7], (const float*)d_in[10]};
    const float* Wh[4] = {(const float*)d_in[2], (const float*)d_in[5],
                          (const float*)d_in[8], (const float*)d_in[11]};
    const float* bs[4] = {(const float*)d_in[3], (const float*)d_in[6],
                          (const float*)d_in[9], (const float*)d_in[12]};
    float* out = (float*)d_out;

    const size_t S  = (size_t)4 * HH * WW * 32;   // one [B,H,W,32] buffer (elements)
    const size_t WT = (size_t)4 * 73728;          // transposed weights (bf16 elems)

    bf16* wt = (bf16*)d_ws;
    bf16* h0 = wt + WT;              // layer0: 4-deep ring (residual read at d+3)
    bf16* h1 = h0 + 4 * S;           // layers 1..3: 2-deep rings
    bf16* h2 = h1 + 2 * S;
    bf16* h3 = h2 + 2 * S;
    float* cb = (float*)(h3 + 2 * S);   // 4 x S fp32 c-state

    prep_weights<<<1152, 256, 0, stream>>>(Wx[0], Wh[0], Wx[1], Wh[1],
                                           Wx[2], Wh[2], Wx[3], Wh[3], wt);

    // Diagonal wavefront: d = t + l, stages (t, l) on one diagonal are independent.
    for (int d = 0; d <= 10; ++d) {
        const int lmin = (d > 7) ? (d - 7) : 0;
        const int lmax = (d < 3) ? d : 3;
        const int nst  = lmax - lmin + 1;
        dim3 grid(WW / 16, HH / 4, nst * 4);
        lstm_stage<<<grid, dim3(128), 0, stream>>>(
            x, wt, bs[0], bs[1], bs[2], bs[3],
            h0, h1, h2, h3, cb, out, d, lmin);
    }
}